// Round 1
// baseline (47.298 us; speedup 1.0000x reference)
//
#include <hip/hip_runtime.h>

// LIF spike scan: x [T=8, B=32, C=128, H=32, W=32] fp32, mem0 [1,128,32,32] fp32
// out spikes [T,B,C,H,W] fp32.
// Per position: mem = 0.25*mem + x_t; spike = (mem > 1); mem = spike ? 0 : mem.

#define T_STEPS 8
#define CHW     (128 * 32 * 32)        // 131072, power of 2
#define N_PER_T (32 * CHW)             // 4194304 elements per timestep
#define N4      (N_PER_T / 4)          // 1048576 float4 items per timestep
#define TAU     0.25f
#define THRESH  1.0f

__global__ __launch_bounds__(256) void lif_scan_kernel(
    const float4* __restrict__ x,      // [T][N4]
    const float4* __restrict__ mem0,   // [CHW/4], broadcast over batch
    float4* __restrict__ out)          // [T][N4]
{
    const int i = blockIdx.x * blockDim.x + threadIdx.x;   // float4 index in one timestep
    // exact grid: N4 = 4096 * 256, no bounds check needed, but keep it cheap+safe
    if (i >= N4) return;

    float4 mem = mem0[i & (CHW / 4 - 1)];

#pragma unroll
    for (int t = 0; t < T_STEPS; ++t) {
        float4 xt = x[(size_t)t * N4 + i];
        float4 s;

        mem.x = TAU * mem.x + xt.x;
        s.x   = (mem.x > THRESH) ? 1.0f : 0.0f;
        mem.x = (mem.x > THRESH) ? 0.0f : mem.x;

        mem.y = TAU * mem.y + xt.y;
        s.y   = (mem.y > THRESH) ? 1.0f : 0.0f;
        mem.y = (mem.y > THRESH) ? 0.0f : mem.y;

        mem.z = TAU * mem.z + xt.z;
        s.z   = (mem.z > THRESH) ? 1.0f : 0.0f;
        mem.z = (mem.z > THRESH) ? 0.0f : mem.z;

        mem.w = TAU * mem.w + xt.w;
        s.w   = (mem.w > THRESH) ? 1.0f : 0.0f;
        mem.w = (mem.w > THRESH) ? 0.0f : mem.w;

        out[(size_t)t * N4 + i] = s;
    }
}

extern "C" void kernel_launch(void* const* d_in, const int* in_sizes, int n_in,
                              void* d_out, int out_size, void* d_ws, size_t ws_size,
                              hipStream_t stream) {
    const float4* x    = (const float4*)d_in[0];
    const float4* mem0 = (const float4*)d_in[1];
    float4* out        = (float4*)d_out;

    const int block = 256;
    const int grid  = N4 / block;      // 4096 blocks
    lif_scan_kernel<<<grid, block, 0, stream>>>(x, mem0, out);
}